// Round 11
// baseline (790.812 us; speedup 1.0000x reference)
//
#include <hip/hip_runtime.h>

// 2-layer GCN on MI355X. CSR-by-target via rank trick (1 atomic/edge).
// dinv folded into GEMM epilogues (g = dinv * (X@W)) -> no norm pass, raw ew in edges.
// g1 stored bf16 to halve agg64 gather traffic; fp32 accumulate everywhere.
// GEMMs occupancy-capped via __launch_bounds__(256,4): r10 showed VGPR=236/occ=9.8%.

struct __align__(8) Edge { int r; float w; };

#define XPAD 68   // 64+4: ng-groups land 16 dwords apart in banks -> <=2-way (free)

__device__ __forceinline__ unsigned short f2bf(float f) {   // RNE
  unsigned u = __float_as_uint(f);
  u = (u + 0x7FFFu + ((u >> 16) & 1u)) >> 16;
  return (unsigned short)u;
}
__device__ __forceinline__ float bf2f(unsigned short h) {
  return __uint_as_float(((unsigned)h) << 16);
}

__global__ __launch_bounds__(256) void zero_cnt(int* cnt, int N) {
  int i = blockIdx.x * 256 + threadIdx.x;
  if (i < N) cnt[i] = 0;
}

// rank[e] = arrival order of edge e at its target (histogram + cursor in one atomic).
// 1.6M random agent-scope atomics: measured HW ceiling ~24 G atomics/s -> ~66us floor.
__global__ __launch_bounds__(256) void rank_kernel(const int* __restrict__ col,
    int* cnt, int* __restrict__ rank, int E) {
  int e = blockIdx.x * 256 + threadIdx.x;
  if (e < E) rank[e] = atomicAdd(&cnt[col[e]], 1);
}

// Single-block exclusive scan, 4 elems/thread, SW-pipelined.
__global__ __launch_bounds__(1024) void scan_kernel(const int* __restrict__ cnt,
    int* __restrict__ indptr, int N) {
  __shared__ int wsum[16];
  int tid = threadIdx.x;
  int lane = tid & 63, wid = tid >> 6;
  int carry = 0;
  int i0 = tid * 4;
  int v0 = (i0 + 0 < N) ? cnt[i0 + 0] : 0;
  int v1 = (i0 + 1 < N) ? cnt[i0 + 1] : 0;
  int v2 = (i0 + 2 < N) ? cnt[i0 + 2] : 0;
  int v3 = (i0 + 3 < N) ? cnt[i0 + 3] : 0;
  for (int base = 0; base < N; base += 4096) {
    int nbase = base + 4096;
    int n0 = 0, n1 = 0, n2 = 0, n3 = 0;
    if (nbase < N) {                    // prefetch next chunk (no carry dependency)
      int j0 = nbase + tid * 4;
      n0 = (j0 + 0 < N) ? cnt[j0 + 0] : 0;
      n1 = (j0 + 1 < N) ? cnt[j0 + 1] : 0;
      n2 = (j0 + 2 < N) ? cnt[j0 + 2] : 0;
      n3 = (j0 + 3 < N) ? cnt[j0 + 3] : 0;
    }
    int s = v0 + v1 + v2 + v3;
    int x = s;
    #pragma unroll
    for (int d = 1; d < 64; d <<= 1) { int y = __shfl_up(x, d); if (lane >= d) x += y; }
    if (lane == 63) wsum[wid] = x;
    __syncthreads();
    if (wid == 0 && lane < 16) {
      int t = wsum[lane];
      #pragma unroll
      for (int d = 1; d < 16; d <<= 1) { int y = __shfl_up(t, d); if (lane >= d) t += y; }
      wsum[lane] = t;
    }
    __syncthreads();
    int waveoff = (wid == 0) ? 0 : wsum[wid - 1];
    int st = base + tid * 4;
    int b0 = carry + waveoff + (x - s);
    if (st + 0 < N) indptr[st + 0] = b0;
    if (st + 1 < N) indptr[st + 1] = b0 + v0;
    if (st + 2 < N) indptr[st + 2] = b0 + v0 + v1;
    if (st + 3 < N) indptr[st + 3] = b0 + v0 + v1 + v2;
    int total = wsum[15];
    __syncthreads();            // protect wsum before next chunk overwrites
    carry += total;
    v0 = n0; v1 = n1; v2 = n2; v3 = n3;
  }
  if (tid == 0) indptr[N] = carry;
}

// Deterministic placement: pos = indptr[col] + rank. NO atomics, one 8B scatter.
__global__ __launch_bounds__(256) void fill_kernel(const int* __restrict__ row,
    const int* __restrict__ col, const float* __restrict__ ew,
    const int* __restrict__ rank, const int* __restrict__ indptr,
    Edge* __restrict__ edges, int E) {
  int e = blockIdx.x * 256 + threadIdx.x;
  if (e < E) {
    int c = col[e];
    Edge ed; ed.r = row[e]; ed.w = ew[e];   // RAW ew (dinv folded into g arrays)
    edges[indptr[c] + rank[e]] = ed;
  }
}

// dinv[c] = 1/sqrt(1 + sum of segment weights). 16 lanes per node, coalesced reads.
__global__ __launch_bounds__(256) void dinv_kernel(const Edge* __restrict__ edges,
    const int* __restrict__ indptr, float* __restrict__ dinv, int N) {
  int tid = threadIdx.x;
  int lane = tid & 63;
  int sub = lane >> 4, j = lane & 15;
  int node = blockIdx.x * 16 + (tid >> 6) * 4 + sub;
  bool valid = node < N;
  int s = 0, e = 0;
  if (valid) { s = indptr[node]; e = indptr[node + 1]; }
  float sum = 0.f;
  for (int b = s; b < e; b += 16) {
    int m = min(16, e - b);
    if (j < m) sum += edges[b + j].w;
  }
  #pragma unroll
  for (int d = 1; d < 16; d <<= 1) sum += __shfl_xor(sum, d, 16);
  if (valid && j == 0) dinv[node] = 1.0f / sqrtf(1.0f + sum);
}

// g1b[N,64](bf16) = dinv ⊙ (X @ W1). Register-tiled: 64-node block, 4x4/thread.
// launch_bounds(256,4): cap VGPR at 128 (r10: unbounded -> 236 VGPR, 9.8% occ, 74us)
__global__ __launch_bounds__(256, 4) void gemm64t(const float* __restrict__ X,
    const float* __restrict__ W, const float* __restrict__ dinv,
    unsigned short* __restrict__ Yb, int N) {
  __shared__ float Xs[64 * XPAD];
  __shared__ float Ws[64 * 64];
  __shared__ float dvs[64];
  int tid = threadIdx.x;
  int nb = blockIdx.x * 64;
  {
    const float4* Wv = (const float4*)W;      // 1024 float4
    float4* Wsv = (float4*)Ws;
    #pragma unroll
    for (int p = 0; p < 4; ++p) Wsv[p * 256 + tid] = Wv[p * 256 + tid];
  }
  if (tid < 64) dvs[tid] = (nb + tid < N) ? dinv[nb + tid] : 0.f;
  #pragma unroll
  for (int p = 0; p < 4; ++p) {
    int g = p * 256 + tid;                    // float4 index in 64x64 tile
    int r = g >> 4, c4 = g & 15;
    int node = nb + r;
    float4 v = make_float4(0.f, 0.f, 0.f, 0.f);
    if (node < N) v = *(const float4*)&X[(size_t)node * 64 + c4 * 4];
    *(float4*)&Xs[r * XPAD + c4 * 4] = v;
  }
  __syncthreads();
  int jg = tid & 15;        // output cols jg*4..+3
  int ng = tid >> 4;        // nodes ng*4..+3
  float acc[4][4] = {};
  for (int k = 0; k < 64; k += 4) {
    float4 xv[4], wv[4];
    #pragma unroll
    for (int i = 0; i < 4; ++i) xv[i] = *(const float4*)&Xs[(ng * 4 + i) * XPAD + k];
    #pragma unroll
    for (int kk = 0; kk < 4; ++kk) wv[kk] = *(const float4*)&Ws[(k + kk) * 64 + jg * 4];
    #pragma unroll
    for (int i = 0; i < 4; ++i) {
      #pragma unroll
      for (int kk = 0; kk < 4; ++kk) {
        float xs = ((const float*)&xv[i])[kk];      // compile-time idx -> registers
        acc[i][0] = fmaf(xs, ((const float*)&wv[kk])[0], acc[i][0]);
        acc[i][1] = fmaf(xs, ((const float*)&wv[kk])[1], acc[i][1]);
        acc[i][2] = fmaf(xs, ((const float*)&wv[kk])[2], acc[i][2]);
        acc[i][3] = fmaf(xs, ((const float*)&wv[kk])[3], acc[i][3]);
      }
    }
  }
  #pragma unroll
  for (int i = 0; i < 4; ++i) {
    int node = nb + ng * 4 + i;
    if (node < N) {
      float dv = dvs[ng * 4 + i];
      ushort4 o;
      o.x = f2bf(dv * acc[i][0]); o.y = f2bf(dv * acc[i][1]);
      o.z = f2bf(dv * acc[i][2]); o.w = f2bf(dv * acc[i][3]);
      *(ushort4*)&Yb[(size_t)node * 64 + jg * 4] = o;
    }
  }
}

// g2[N,16](fp32) = dinv ⊙ (Xh @ W2). 64-node block, 1 node x 4 cols per thread.
__global__ __launch_bounds__(256, 4) void gemm16t(const float* __restrict__ Xh,
    const float* __restrict__ W2, const float* __restrict__ dinv,
    float* __restrict__ Y, int N) {
  __shared__ float Xs[64 * XPAD];
  __shared__ float Ws[64 * 16];
  __shared__ float dvs[64];
  int tid = threadIdx.x;
  int nb = blockIdx.x * 64;
  ((float4*)Ws)[tid] = ((const float4*)W2)[tid];  // 256 float4 exactly
  if (tid < 64) dvs[tid] = (nb + tid < N) ? dinv[nb + tid] : 0.f;
  #pragma unroll
  for (int p = 0; p < 4; ++p) {
    int g = p * 256 + tid;
    int r = g >> 4, c4 = g & 15;
    int node = nb + r;
    float4 v = make_float4(0.f, 0.f, 0.f, 0.f);
    if (node < N) v = *(const float4*)&Xh[(size_t)node * 64 + c4 * 4];
    *(float4*)&Xs[r * XPAD + c4 * 4] = v;
  }
  __syncthreads();
  int node_l = tid >> 2;    // 0..63
  int jg = tid & 3;         // cols jg*4..+3
  float acc[4] = {};
  for (int k = 0; k < 64; k += 4) {
    float4 xv = *(const float4*)&Xs[node_l * XPAD + k];
    #pragma unroll
    for (int kk = 0; kk < 4; ++kk) {
      float4 wv = *(const float4*)&Ws[(k + kk) * 16 + jg * 4];
      float xs = ((const float*)&xv)[kk];
      acc[0] = fmaf(xs, wv.x, acc[0]);
      acc[1] = fmaf(xs, wv.y, acc[1]);
      acc[2] = fmaf(xs, wv.z, acc[2]);
      acc[3] = fmaf(xs, wv.w, acc[3]);
    }
  }
  int node = nb + node_l;
  if (node < N) {
    float dv = dvs[node_l];
    *(float4*)&Y[(size_t)node * 16 + jg * 4] =
        make_float4(dv * acc[0], dv * acc[1], dv * acc[2], dv * acc[3]);
  }
}

// hrelu[c,:] = relu( di*( sum ew*g1[r] + g1[c] ) + b1 ). Wave per node.
__global__ __launch_bounds__(256) void agg64(const unsigned short* __restrict__ g1b,
    const int* __restrict__ indptr, const Edge* __restrict__ edges,
    const float* __restrict__ dinv, const float* __restrict__ b1,
    float* __restrict__ hout, int N) {
  __shared__ Edge eds[4][64];
  int tid = threadIdx.x;
  int lane = tid & 63;
  int wid = tid >> 6;
  int node = blockIdx.x * 4 + wid;
  if (node >= N) return;                       // wave-uniform guard
  int s = indptr[node], eend = indptr[node + 1];
  float di = dinv[node];
  float selfv = bf2f(g1b[(size_t)node * 64 + lane]);   // raw g1[c] (self)
  float acc = 0.f, accB = 0.f;
  for (int base = s; base < eend; base += 64) {
    int m = min(64, eend - base);
    if (lane < m) eds[wid][lane] = edges[base + lane];  // coalesced 512B + ds_write
    // wave-private region: compiler-inserted lgkmcnt ordering suffices, no barrier
    int t = 0;
    for (; t + 1 < m; t += 2) {
      Edge e0 = eds[wid][t];        // uniform addr -> broadcast, conflict-free
      Edge e1 = eds[wid][t + 1];
      acc  = fmaf(e0.w, bf2f(g1b[(size_t)e0.r * 64 + lane]), acc);  // 128B/row gather
      accB = fmaf(e1.w, bf2f(g1b[(size_t)e1.r * 64 + lane]), accB);
    }
    if (t < m) {
      Edge e0 = eds[wid][t];
      acc = fmaf(e0.w, bf2f(g1b[(size_t)e0.r * 64 + lane]), acc);
    }
  }
  float res = fmaf(di, acc + accB + selfv, b1[lane]);
  hout[(size_t)node * 64 + lane] = fmaxf(res, 0.f);
}

// out[c,:] = di*( sum ew*g2[r] + g2[c] ) + b2. 16 lanes per node, LDS-staged edges.
__global__ __launch_bounds__(256) void agg16(const float* __restrict__ g2,
    const int* __restrict__ indptr, const Edge* __restrict__ edges,
    const float* __restrict__ dinv, const float* __restrict__ b2,
    float* __restrict__ out, int N) {
  __shared__ Edge eds[4][4][17];   // [wave][sub][edge], pad 17: subs 2 banks apart
  int tid = threadIdx.x;
  int lane = tid & 63;
  int wid = tid >> 6;
  int sub = lane >> 4, j = lane & 15;
  int node = blockIdx.x * 16 + wid * 4 + sub;
  bool valid = node < N;
  int s = 0, eend = 0;
  float di = 0.f, selfv = 0.f;
  if (valid) {
    s = indptr[node]; eend = indptr[node + 1];
    di = dinv[node];
    selfv = g2[(size_t)node * 16 + j];
  }
  float acc = 0.f, accB = 0.f;
  for (int base = s; base < eend; base += 16) {
    int m = min(16, eend - base);
    if (j < m) eds[wid][sub][j] = edges[base + j];
    int t = 0;
    for (; t + 1 < m; t += 2) {
      Edge e0 = eds[wid][sub][t];
      Edge e1 = eds[wid][sub][t + 1];
      acc  = fmaf(e0.w, g2[(size_t)e0.r * 16 + j], acc);
      accB = fmaf(e1.w, g2[(size_t)e1.r * 16 + j], accB);
    }
    if (t < m) {
      Edge e0 = eds[wid][sub][t];
      acc = fmaf(e0.w, g2[(size_t)e0.r * 16 + j], acc);
    }
  }
  if (valid) out[(size_t)node * 16 + j] = fmaf(di, acc + accB + selfv, b2[j]);
}

extern "C" void kernel_launch(void* const* d_in, const int* in_sizes, int n_in,
                              void* d_out, int out_size, void* d_ws, size_t ws_size,
                              hipStream_t stream) {
  const float* X   = (const float*)d_in[0];
  const int*   eix = (const int*)d_in[1];   // int32 on device (verified by passing bench)
  const float* ew  = (const float*)d_in[2];
  const float* W1  = (const float*)d_in[3];
  const float* b1  = (const float*)d_in[4];
  const float* W2  = (const float*)d_in[5];
  const float* b2  = (const float*)d_in[6];
  float* out = (float*)d_out;

  const int N = in_sizes[0] / 64;
  const int E = in_sizes[1] / 2;
  const int* row = eix;
  const int* col = eix + E;

  char* ws = (char*)d_ws;
  size_t off = 0;
  auto alloc = [&](size_t bytes) -> void* {
    void* p = ws + off;
    off += (bytes + 255) & ~(size_t)255;
    return p;
  };
  int*   cnt    = (int*)  alloc((size_t)N * 4);
  int*   indptr = (int*)  alloc(((size_t)N + 1) * 4);
  int*   rank   = (int*)  alloc((size_t)E * 4);
  Edge*  edges  = (Edge*) alloc((size_t)E * 8);
  float* dinv   = (float*)alloc((size_t)N * 4);
  unsigned short* g1b = (unsigned short*)alloc((size_t)N * 64 * 2);
  float* hrelu  = (float*)alloc((size_t)N * 64 * 4);
  float* g2     = (float*)alloc((size_t)N * 16 * 4);
  if (off > ws_size) return;  // fail loudly: output stays poisoned

  int nbN = (N + 255) / 256;
  int nbE = (E + 255) / 256;
  int nbT = (N + 63) / 64;

  zero_cnt   <<<nbN, 256, 0, stream>>>(cnt, N);
  rank_kernel<<<nbE, 256, 0, stream>>>(col, cnt, rank, E);
  scan_kernel<<<1, 1024, 0, stream>>>(cnt, indptr, N);
  fill_kernel<<<nbE, 256, 0, stream>>>(row, col, ew, rank, indptr, edges, E);
  dinv_kernel<<<(N + 15) / 16, 256, 0, stream>>>(edges, indptr, dinv, N);

  gemm64t<<<nbT, 256, 0, stream>>>(X, W1, dinv, g1b, N);
  agg64  <<<(N + 3) / 4, 256, 0, stream>>>(g1b, indptr, edges, dinv, b1, hrelu, N);
  gemm16t<<<nbT, 256, 0, stream>>>(hrelu, W2, dinv, g2, N);
  agg16  <<<(N + 15) / 16, 256, 0, stream>>>(g2, indptr, edges, dinv, b2, out, N);
}

// Round 13
// 360.563 us; speedup vs baseline: 2.1933x; 2.1933x over previous
//
#include <hip/hip_runtime.h>

// 2-layer GCN on MI355X. CSR-by-target via rank trick (1 atomic/edge).
// dinv folded into GEMM epilogues; g1 bf16 (halves agg64 gather traffic).
// GEMM k-loops: #pragma unroll 1 — r10's VGPR=236 came from full 16-step unroll
// (pipelined LDS loads); r11's launch_bounds(256,4) "fix" forced VGPR=64 and
// spilled 1.38GB/dispatch to scratch (435us). Bound the CAUSE, not the allocator.

struct __align__(8) Edge { int r; float w; };

#define XPAD 68   // 64+4: ng-groups land 16 dwords apart in banks -> <=2-way (free)

__device__ __forceinline__ unsigned short f2bf(float f) {   // RNE
  unsigned u = __float_as_uint(f);
  u = (u + 0x7FFFu + ((u >> 16) & 1u)) >> 16;
  return (unsigned short)u;
}
__device__ __forceinline__ float bf2f(unsigned short h) {
  return __uint_as_float(((unsigned)h) << 16);
}

__global__ __launch_bounds__(256) void zero_cnt(int* cnt, int N) {
  int i = blockIdx.x * 256 + threadIdx.x;
  if (i < N) cnt[i] = 0;
}

// rank[e] = arrival order of edge e at its target (histogram + cursor in one atomic).
// 1.6M random agent-scope atomics: measured HW ceiling ~24 G atomics/s -> ~66us floor.
__global__ __launch_bounds__(256) void rank_kernel(const int* __restrict__ col,
    int* cnt, int* __restrict__ rank, int E) {
  int e = blockIdx.x * 256 + threadIdx.x;
  if (e < E) rank[e] = atomicAdd(&cnt[col[e]], 1);
}

// Single-block exclusive scan, 4 elems/thread, SW-pipelined.
__global__ __launch_bounds__(1024) void scan_kernel(const int* __restrict__ cnt,
    int* __restrict__ indptr, int N) {
  __shared__ int wsum[16];
  int tid = threadIdx.x;
  int lane = tid & 63, wid = tid >> 6;
  int carry = 0;
  int i0 = tid * 4;
  int v0 = (i0 + 0 < N) ? cnt[i0 + 0] : 0;
  int v1 = (i0 + 1 < N) ? cnt[i0 + 1] : 0;
  int v2 = (i0 + 2 < N) ? cnt[i0 + 2] : 0;
  int v3 = (i0 + 3 < N) ? cnt[i0 + 3] : 0;
  for (int base = 0; base < N; base += 4096) {
    int nbase = base + 4096;
    int n0 = 0, n1 = 0, n2 = 0, n3 = 0;
    if (nbase < N) {                    // prefetch next chunk (no carry dependency)
      int j0 = nbase + tid * 4;
      n0 = (j0 + 0 < N) ? cnt[j0 + 0] : 0;
      n1 = (j0 + 1 < N) ? cnt[j0 + 1] : 0;
      n2 = (j0 + 2 < N) ? cnt[j0 + 2] : 0;
      n3 = (j0 + 3 < N) ? cnt[j0 + 3] : 0;
    }
    int s = v0 + v1 + v2 + v3;
    int x = s;
    #pragma unroll
    for (int d = 1; d < 64; d <<= 1) { int y = __shfl_up(x, d); if (lane >= d) x += y; }
    if (lane == 63) wsum[wid] = x;
    __syncthreads();
    if (wid == 0 && lane < 16) {
      int t = wsum[lane];
      #pragma unroll
      for (int d = 1; d < 16; d <<= 1) { int y = __shfl_up(t, d); if (lane >= d) t += y; }
      wsum[lane] = t;
    }
    __syncthreads();
    int waveoff = (wid == 0) ? 0 : wsum[wid - 1];
    int st = base + tid * 4;
    int b0 = carry + waveoff + (x - s);
    if (st + 0 < N) indptr[st + 0] = b0;
    if (st + 1 < N) indptr[st + 1] = b0 + v0;
    if (st + 2 < N) indptr[st + 2] = b0 + v0 + v1;
    if (st + 3 < N) indptr[st + 3] = b0 + v0 + v1 + v2;
    int total = wsum[15];
    __syncthreads();            // protect wsum before next chunk overwrites
    carry += total;
    v0 = n0; v1 = n1; v2 = n2; v3 = n3;
  }
  if (tid == 0) indptr[N] = carry;
}

// Deterministic placement: pos = indptr[col] + rank. NO atomics, one 8B scatter.
__global__ __launch_bounds__(256) void fill_kernel(const int* __restrict__ row,
    const int* __restrict__ col, const float* __restrict__ ew,
    const int* __restrict__ rank, const int* __restrict__ indptr,
    Edge* __restrict__ edges, int E) {
  int e = blockIdx.x * 256 + threadIdx.x;
  if (e < E) {
    int c = col[e];
    Edge ed; ed.r = row[e]; ed.w = ew[e];   // RAW ew (dinv folded into g arrays)
    edges[indptr[c] + rank[e]] = ed;
  }
}

// dinv[c] = 1/sqrt(1 + sum of segment weights). 16 lanes per node, coalesced reads.
__global__ __launch_bounds__(256) void dinv_kernel(const Edge* __restrict__ edges,
    const int* __restrict__ indptr, float* __restrict__ dinv, int N) {
  int tid = threadIdx.x;
  int lane = tid & 63;
  int sub = lane >> 4, j = lane & 15;
  int node = blockIdx.x * 16 + (tid >> 6) * 4 + sub;
  bool valid = node < N;
  int s = 0, e = 0;
  if (valid) { s = indptr[node]; e = indptr[node + 1]; }
  float sum = 0.f;
  for (int b = s; b < e; b += 16) {
    int m = min(16, e - b);
    if (j < m) sum += edges[b + j].w;
  }
  #pragma unroll
  for (int d = 1; d < 16; d <<= 1) sum += __shfl_xor(sum, d, 16);
  if (valid && j == 0) dinv[node] = 1.0f / sqrtf(1.0f + sum);
}

// g1b[N,64](bf16) = dinv ⊙ (X @ W1). Register-tiled: 64-node block, 4x4/thread.
// k-loop NOT unrolled: keeps live set ~70 VGPR, no spill, no occupancy cliff.
__global__ __launch_bounds__(256) void gemm64t(const float* __restrict__ X,
    const float* __restrict__ W, const float* __restrict__ dinv,
    unsigned short* __restrict__ Yb, int N) {
  __shared__ float Xs[64 * XPAD];
  __shared__ float Ws[64 * 64];
  __shared__ float dvs[64];
  int tid = threadIdx.x;
  int nb = blockIdx.x * 64;
  {
    const float4* Wv = (const float4*)W;      // 1024 float4
    float4* Wsv = (float4*)Ws;
    #pragma unroll
    for (int p = 0; p < 4; ++p) Wsv[p * 256 + tid] = Wv[p * 256 + tid];
  }
  if (tid < 64) dvs[tid] = (nb + tid < N) ? dinv[nb + tid] : 0.f;
  #pragma unroll
  for (int p = 0; p < 4; ++p) {
    int g = p * 256 + tid;                    // float4 index in 64x64 tile
    int r = g >> 4, c4 = g & 15;
    int node = nb + r;
    float4 v = make_float4(0.f, 0.f, 0.f, 0.f);
    if (node < N) v = *(const float4*)&X[(size_t)node * 64 + c4 * 4];
    *(float4*)&Xs[r * XPAD + c4 * 4] = v;
  }
  __syncthreads();
  int jg = tid & 15;        // output cols jg*4..+3
  int ng = tid >> 4;        // nodes ng*4..+3
  float acc[4][4] = {};
  #pragma unroll 1
  for (int k = 0; k < 64; k += 4) {
    float4 xv[4], wv[4];
    #pragma unroll
    for (int i = 0; i < 4; ++i) xv[i] = *(const float4*)&Xs[(ng * 4 + i) * XPAD + k];
    #pragma unroll
    for (int kk = 0; kk < 4; ++kk) wv[kk] = *(const float4*)&Ws[(k + kk) * 64 + jg * 4];
    #pragma unroll
    for (int i = 0; i < 4; ++i) {
      #pragma unroll
      for (int kk = 0; kk < 4; ++kk) {
        float xs = ((const float*)&xv[i])[kk];      // compile-time idx -> registers
        acc[i][0] = fmaf(xs, ((const float*)&wv[kk])[0], acc[i][0]);
        acc[i][1] = fmaf(xs, ((const float*)&wv[kk])[1], acc[i][1]);
        acc[i][2] = fmaf(xs, ((const float*)&wv[kk])[2], acc[i][2]);
        acc[i][3] = fmaf(xs, ((const float*)&wv[kk])[3], acc[i][3]);
      }
    }
  }
  #pragma unroll
  for (int i = 0; i < 4; ++i) {
    int node = nb + ng * 4 + i;
    if (node < N) {
      float dv = dvs[ng * 4 + i];
      ushort4 o;
      o.x = f2bf(dv * acc[i][0]); o.y = f2bf(dv * acc[i][1]);
      o.z = f2bf(dv * acc[i][2]); o.w = f2bf(dv * acc[i][3]);
      *(ushort4*)&Yb[(size_t)node * 64 + jg * 4] = o;
    }
  }
}

// g2[N,16](fp32) = dinv ⊙ (Xh @ W2). 64-node block, 1 node x 4 cols per thread.
__global__ __launch_bounds__(256) void gemm16t(const float* __restrict__ Xh,
    const float* __restrict__ W2, const float* __restrict__ dinv,
    float* __restrict__ Y, int N) {
  __shared__ float Xs[64 * XPAD];
  __shared__ float Ws[64 * 16];
  __shared__ float dvs[64];
  int tid = threadIdx.x;
  int nb = blockIdx.x * 64;
  ((float4*)Ws)[tid] = ((const float4*)W2)[tid];  // 256 float4 exactly
  if (tid < 64) dvs[tid] = (nb + tid < N) ? dinv[nb + tid] : 0.f;
  #pragma unroll
  for (int p = 0; p < 4; ++p) {
    int g = p * 256 + tid;
    int r = g >> 4, c4 = g & 15;
    int node = nb + r;
    float4 v = make_float4(0.f, 0.f, 0.f, 0.f);
    if (node < N) v = *(const float4*)&Xh[(size_t)node * 64 + c4 * 4];
    *(float4*)&Xs[r * XPAD + c4 * 4] = v;
  }
  __syncthreads();
  int node_l = tid >> 2;    // 0..63
  int jg = tid & 3;         // cols jg*4..+3
  float acc[4] = {};
  #pragma unroll 1
  for (int k = 0; k < 64; k += 4) {
    float4 xv = *(const float4*)&Xs[node_l * XPAD + k];
    #pragma unroll
    for (int kk = 0; kk < 4; ++kk) {
      float4 wv = *(const float4*)&Ws[(k + kk) * 16 + jg * 4];
      float xs = ((const float*)&xv)[kk];
      acc[0] = fmaf(xs, wv.x, acc[0]);
      acc[1] = fmaf(xs, wv.y, acc[1]);
      acc[2] = fmaf(xs, wv.z, acc[2]);
      acc[3] = fmaf(xs, wv.w, acc[3]);
    }
  }
  int node = nb + node_l;
  if (node < N) {
    float dv = dvs[node_l];
    *(float4*)&Y[(size_t)node * 16 + jg * 4] =
        make_float4(dv * acc[0], dv * acc[1], dv * acc[2], dv * acc[3]);
  }
}

// hrelu[c,:] = relu( di*( sum ew*g1[r] + g1[c] ) + b1 ). Wave per node.
__global__ __launch_bounds__(256) void agg64(const unsigned short* __restrict__ g1b,
    const int* __restrict__ indptr, const Edge* __restrict__ edges,
    const float* __restrict__ dinv, const float* __restrict__ b1,
    float* __restrict__ hout, int N) {
  __shared__ Edge eds[4][64];
  int tid = threadIdx.x;
  int lane = tid & 63;
  int wid = tid >> 6;
  int node = blockIdx.x * 4 + wid;
  if (node >= N) return;                       // wave-uniform guard
  int s = indptr[node], eend = indptr[node + 1];
  float di = dinv[node];
  float selfv = bf2f(g1b[(size_t)node * 64 + lane]);   // raw g1[c] (self)
  float acc = 0.f, accB = 0.f;
  for (int base = s; base < eend; base += 64) {
    int m = min(64, eend - base);
    if (lane < m) eds[wid][lane] = edges[base + lane];  // coalesced 512B + ds_write
    // wave-private region: compiler-inserted lgkmcnt ordering suffices, no barrier
    int t = 0;
    for (; t + 1 < m; t += 2) {
      Edge e0 = eds[wid][t];        // uniform addr -> broadcast, conflict-free
      Edge e1 = eds[wid][t + 1];
      acc  = fmaf(e0.w, bf2f(g1b[(size_t)e0.r * 64 + lane]), acc);  // 128B/row gather
      accB = fmaf(e1.w, bf2f(g1b[(size_t)e1.r * 64 + lane]), accB);
    }
    if (t < m) {
      Edge e0 = eds[wid][t];
      acc = fmaf(e0.w, bf2f(g1b[(size_t)e0.r * 64 + lane]), acc);
    }
  }
  float res = fmaf(di, acc + accB + selfv, b1[lane]);
  hout[(size_t)node * 64 + lane] = fmaxf(res, 0.f);
}

// out[c,:] = di*( sum ew*g2[r] + g2[c] ) + b2. 16 lanes per node, LDS-staged edges.
__global__ __launch_bounds__(256) void agg16(const float* __restrict__ g2,
    const int* __restrict__ indptr, const Edge* __restrict__ edges,
    const float* __restrict__ dinv, const float* __restrict__ b2,
    float* __restrict__ out, int N) {
  __shared__ Edge eds[4][4][17];   // [wave][sub][edge], pad 17: subs 2 banks apart
  int tid = threadIdx.x;
  int lane = tid & 63;
  int wid = tid >> 6;
  int sub = lane >> 4, j = lane & 15;
  int node = blockIdx.x * 16 + wid * 4 + sub;
  bool valid = node < N;
  int s = 0, eend = 0;
  float di = 0.f, selfv = 0.f;
  if (valid) {
    s = indptr[node]; eend = indptr[node + 1];
    di = dinv[node];
    selfv = g2[(size_t)node * 16 + j];
  }
  float acc = 0.f, accB = 0.f;
  for (int base = s; base < eend; base += 16) {
    int m = min(16, eend - base);
    if (j < m) eds[wid][sub][j] = edges[base + j];
    int t = 0;
    for (; t + 1 < m; t += 2) {
      Edge e0 = eds[wid][sub][t];
      Edge e1 = eds[wid][sub][t + 1];
      acc  = fmaf(e0.w, g2[(size_t)e0.r * 16 + j], acc);
      accB = fmaf(e1.w, g2[(size_t)e1.r * 16 + j], accB);
    }
    if (t < m) {
      Edge e0 = eds[wid][sub][t];
      acc = fmaf(e0.w, g2[(size_t)e0.r * 16 + j], acc);
    }
  }
  if (valid) out[(size_t)node * 16 + j] = fmaf(di, acc + accB + selfv, b2[j]);
}

extern "C" void kernel_launch(void* const* d_in, const int* in_sizes, int n_in,
                              void* d_out, int out_size, void* d_ws, size_t ws_size,
                              hipStream_t stream) {
  const float* X   = (const float*)d_in[0];
  const int*   eix = (const int*)d_in[1];   // int32 on device (verified by passing bench)
  const float* ew  = (const float*)d_in[2];
  const float* W1  = (const float*)d_in[3];
  const float* b1  = (const float*)d_in[4];
  const float* W2  = (const float*)d_in[5];
  const float* b2  = (const float*)d_in[6];
  float* out = (float*)d_out;

  const int N = in_sizes[0] / 64;
  const int E = in_sizes[1] / 2;
  const int* row = eix;
  const int* col = eix + E;

  char* ws = (char*)d_ws;
  size_t off = 0;
  auto alloc = [&](size_t bytes) -> void* {
    void* p = ws + off;
    off += (bytes + 255) & ~(size_t)255;
    return p;
  };
  int*   cnt    = (int*)  alloc((size_t)N * 4);
  int*   indptr = (int*)  alloc(((size_t)N + 1) * 4);
  int*   rank   = (int*)  alloc((size_t)E * 4);
  Edge*  edges  = (Edge*) alloc((size_t)E * 8);
  float* dinv   = (float*)alloc((size_t)N * 4);
  unsigned short* g1b = (unsigned short*)alloc((size_t)N * 64 * 2);
  float* hrelu  = (float*)alloc((size_t)N * 64 * 4);
  float* g2     = (float*)alloc((size_t)N * 16 * 4);
  if (off > ws_size) return;  // fail loudly: output stays poisoned

  int nbN = (N + 255) / 256;
  int nbE = (E + 255) / 256;
  int nbT = (N + 63) / 64;

  zero_cnt   <<<nbN, 256, 0, stream>>>(cnt, N);
  rank_kernel<<<nbE, 256, 0, stream>>>(col, cnt, rank, E);
  scan_kernel<<<1, 1024, 0, stream>>>(cnt, indptr, N);
  fill_kernel<<<nbE, 256, 0, stream>>>(row, col, ew, rank, indptr, edges, E);
  dinv_kernel<<<(N + 15) / 16, 256, 0, stream>>>(edges, indptr, dinv, N);

  gemm64t<<<nbT, 256, 0, stream>>>(X, W1, dinv, g1b, N);
  agg64  <<<(N + 3) / 4, 256, 0, stream>>>(g1b, indptr, edges, dinv, b1, hrelu, N);
  gemm16t<<<nbT, 256, 0, stream>>>(hrelu, W2, dinv, g2, N);
  agg16  <<<(N + 15) / 16, 256, 0, stream>>>(g2, indptr, edges, dinv, b2, out, N);
}